// Round 1
// baseline (1103.036 us; speedup 1.0000x reference)
//
// Round 1: correctness-first full-bf16-MFMA transformer encoder.
// Structure: one templated BT-GEMM (128x128 tile, BK=32, VGPR->LDS staging),
// batched variants for attention; softmax in-place on d_out; shuffle-reduce LN.
#include <hip/hip_runtime.h>
#include <hip/hip_bf16.h>

#define B_ 8
#define L_ 512
#define D_ 512
#define H_ 8
#define F_ 2048
#define NL_ 4
#define BL 4096            // B_*L_
#define EPS_ 1e-5f

typedef __bf16 bf16_t;
typedef bf16_t bf16x8 __attribute__((ext_vector_type(8)));
typedef float f32x4 __attribute__((ext_vector_type(4)));
typedef unsigned short u16x8 __attribute__((ext_vector_type(8)));

__device__ __forceinline__ unsigned short f2b_rn(float f) {
  unsigned u = __builtin_bit_cast(unsigned, f);
  u = (u + 0x7fffu + ((u >> 16) & 1u)) >> 16;
  return (unsigned short)u;
}

// C[M,N] = relu?(scale * A[M,K] @ B[N,K]^T + bias[N]); optional fp32 and bf16 outputs.
// Batched via blockIdx.z with (z/zi, z%zi) stride decomposition for A/B/C.
// Layout requirements (all satisfied by our shapes): M%BM==0, N%BN==0, K%32==0,
// all row strides multiples of 8 elements (16B-aligned vector loads).
template<int BM, int BN, int MT, int NT>
__global__ __launch_bounds__(256)
void gemm_bt(const unsigned short* __restrict__ A, int lda, long sAo, long sAi,
             const unsigned short* __restrict__ Bm, int ldb, long sBo, long sBi,
             float* __restrict__ Cf, unsigned short* __restrict__ Cb, int ldc,
             long sCo, long sCi,
             const float* __restrict__ bias, int K, float scale, int relu, int zi)
{
  static_assert(BM == MT * 32 && BN == NT * 32, "waves are 2x2");
  __shared__ unsigned short As[BM * 32];
  __shared__ unsigned short Bs[BN * 32];
  const int tid  = threadIdx.x;
  const int lane = tid & 63;
  const int wave = tid >> 6;
  const int wm = (wave >> 1) * (MT * 16);
  const int wn = (wave & 1) * (NT * 16);
  const int m0 = blockIdx.x * BM;
  const int n0 = blockIdx.y * BN;
  const int z  = blockIdx.z;
  const long offA = (long)(z / zi) * sAo + (long)(z % zi) * sAi;
  const long offB = (long)(z / zi) * sBo + (long)(z % zi) * sBi;
  const long offC = (long)(z / zi) * sCo + (long)(z % zi) * sCi;

  f32x4 acc[MT][NT] = {};

  for (int k0 = 0; k0 < K; k0 += 32) {
    __syncthreads();
#pragma unroll
    for (int j = 0; j < BM / 64; ++j) {
      int c = tid + j * 256;
      int r = c >> 2, cc = (c & 3) * 8;
      *(u16x8*)(&As[c * 8]) =
          *(const u16x8*)(A + offA + (long)(m0 + r) * lda + (k0 + cc));
    }
#pragma unroll
    for (int j = 0; j < BN / 64; ++j) {
      int c = tid + j * 256;
      int r = c >> 2, cc = (c & 3) * 8;
      *(u16x8*)(&Bs[c * 8]) =
          *(const u16x8*)(Bm + offB + (long)(n0 + r) * ldb + (k0 + cc));
    }
    __syncthreads();
    // A-frag: A[m=lane&15][k=(lane>>4)*8+j]; B-frag: B[n=lane&15][k=...]
    bf16x8 af[MT], bfr[NT];
#pragma unroll
    for (int mt = 0; mt < MT; ++mt)
      af[mt] = *(const bf16x8*)(&As[(wm + mt * 16 + (lane & 15)) * 32 + (lane >> 4) * 8]);
#pragma unroll
    for (int nt = 0; nt < NT; ++nt)
      bfr[nt] = *(const bf16x8*)(&Bs[(wn + nt * 16 + (lane & 15)) * 32 + (lane >> 4) * 8]);
#pragma unroll
    for (int mt = 0; mt < MT; ++mt)
#pragma unroll
      for (int nt = 0; nt < NT; ++nt)
        acc[mt][nt] = __builtin_amdgcn_mfma_f32_16x16x32_bf16(af[mt], bfr[nt], acc[mt][nt], 0, 0, 0);
  }

  // C/D layout (verified m89/m91): col=lane&15, row=(lane>>4)*4+r
#pragma unroll
  for (int nt = 0; nt < NT; ++nt) {
    const int col = n0 + wn + nt * 16 + (lane & 15);
    const float bb = bias ? bias[col] : 0.f;
#pragma unroll
    for (int mt = 0; mt < MT; ++mt) {
#pragma unroll
      for (int r = 0; r < 4; ++r) {
        const int row = m0 + wm + mt * 16 + (lane >> 4) * 4 + r;
        float v = acc[mt][nt][r] * scale + bb;
        if (relu) v = fmaxf(v, 0.f);
        const long o = offC + (long)row * ldc + col;
        if (Cf) Cf[o] = v;
        if (Cb) Cb[o] = f2b_rn(v);
      }
    }
  }
}

// In-place softmax over rows of 512 fp32; also emits bf16 copy.
__global__ __launch_bounds__(256)
void softmax_rows(float* __restrict__ p, unsigned short* __restrict__ pb) {
  const long row = blockIdx.x;
  float* r = p + row * 512;
  const int t = threadIdx.x;
  const int wave = t >> 6, lane = t & 63;
  float v0 = r[t], v1 = r[t + 256];
  float m = fmaxf(v0, v1);
  for (int o = 32; o > 0; o >>= 1) m = fmaxf(m, __shfl_down(m, o));
  __shared__ float red[8];
  if (lane == 0) red[wave] = m;
  __syncthreads();
  m = fmaxf(fmaxf(red[0], red[1]), fmaxf(red[2], red[3]));
  float e0 = __expf(v0 - m), e1 = __expf(v1 - m);
  float s = e0 + e1;
  for (int o = 32; o > 0; o >>= 1) s += __shfl_down(s, o);
  if (lane == 0) red[4 + wave] = s;
  __syncthreads();
  s = red[4] + red[5] + red[6] + red[7];
  const float inv = 1.f / s;
  const float a0 = e0 * inv, a1 = e1 * inv;
  r[t] = a0; r[t + 256] = a1;
  pb[row * 512 + t] = f2b_rn(a0);
  pb[row * 512 + t + 256] = f2b_rn(a1);
}

// out = LayerNorm(a + b) * g + be ; writes fp32 + bf16
__global__ __launch_bounds__(256)
void resid_ln(const float* __restrict__ a, const float* __restrict__ b,
              const float* __restrict__ g, const float* __restrict__ be,
              float* __restrict__ outf, unsigned short* __restrict__ outb) {
  const long row = blockIdx.x;
  const int t = threadIdx.x;
  const int wave = t >> 6, lane = t & 63;
  const float v0 = a[row * 512 + t] + b[row * 512 + t];
  const float v1 = a[row * 512 + t + 256] + b[row * 512 + t + 256];
  float s = v0 + v1, s2 = v0 * v0 + v1 * v1;
  for (int o = 32; o > 0; o >>= 1) { s += __shfl_down(s, o); s2 += __shfl_down(s2, o); }
  __shared__ float red[16];
  if (lane == 0) { red[wave] = s; red[8 + wave] = s2; }
  __syncthreads();
  s  = red[0] + red[1] + red[2] + red[3];
  s2 = red[8] + red[9] + red[10] + red[11];
  const float mu  = s * (1.f / 512.f);
  const float var = s2 * (1.f / 512.f) - mu * mu;
  const float inv = rsqrtf(var + EPS_);
  const float y0 = (v0 - mu) * inv * g[t] + be[t];
  const float y1 = (v1 - mu) * inv * g[t + 256] + be[t + 256];
  outf[row * 512 + t] = y0;
  outf[row * 512 + t + 256] = y1;
  outb[row * 512 + t] = f2b_rn(y0);
  outb[row * 512 + t + 256] = f2b_rn(y1);
}

// vT[z=(b*8+h)][d][s] = qkv_bf[(b*512+s)*1536 + 1024 + h*64 + d]
__global__ __launch_bounds__(256)
void pack_vT(const unsigned short* __restrict__ qkv, unsigned short* __restrict__ vT) {
  const int z = blockIdx.x;
  const int bb = z >> 3, h = z & 7;
  const int idx = blockIdx.y * 256 + threadIdx.x;  // < 64*512
  const int d = idx >> 9, s = idx & 511;
  vT[(long)z * 32768 + idx] = qkv[((long)(bb * 512 + s)) * 1536 + 1024 + h * 64 + d];
}

__global__ void f2b_arr(const float* __restrict__ in, unsigned short* __restrict__ out, long n) {
  long i = (long)blockIdx.x * 256 + threadIdx.x;
  const long stride = (long)gridDim.x * 256;
  for (; i < n; i += stride) out[i] = f2b_rn(in[i]);
}

__global__ void copy_conv(const float* __restrict__ in, float* __restrict__ outf,
                          unsigned short* __restrict__ outb, long n) {
  long i = (long)blockIdx.x * 256 + threadIdx.x;
  const long stride = (long)gridDim.x * 256;
  for (; i < n; i += stride) { float v = in[i]; outf[i] = v; outb[i] = f2b_rn(v); }
}

extern "C" void kernel_launch(void* const* d_in, const int* in_sizes, int n_in,
                              void* d_out, int out_size, void* d_ws, size_t ws_size,
                              hipStream_t stream) {
  const float* src  = (const float*)d_in[0];
  const float* Wqkv = (const float*)d_in[1];
  const float* bqkv = (const float*)d_in[2];
  const float* Wo   = (const float*)d_in[3];
  const float* bo   = (const float*)d_in[4];
  const float* W1   = (const float*)d_in[5];
  const float* b1   = (const float*)d_in[6];
  const float* W2   = (const float*)d_in[7];
  const float* b2   = (const float*)d_in[8];
  const float* g1   = (const float*)d_in[9];
  const float* be1  = (const float*)d_in[10];
  const float* g2   = (const float*)d_in[11];
  const float* be2  = (const float*)d_in[12];

  char* p = (char*)d_ws;
  auto take = [&](size_t bytes) { void* r = (void*)p; p += (bytes + 255) & ~(size_t)255; return r; };
  float* x        = (float*)take((size_t)BL * 512 * 4);
  float* x1       = (float*)take((size_t)BL * 512 * 4);
  float* attn_out = (float*)take((size_t)BL * 512 * 4);
  float* ff2      = (float*)take((size_t)BL * 512 * 4);
  unsigned short* xbf    = (unsigned short*)take((size_t)BL * 512 * 2);
  unsigned short* qkvbf  = (unsigned short*)take((size_t)BL * 1536 * 2);
  unsigned short* attnbf = (unsigned short*)take((size_t)64 * 512 * 512 * 2);
  unsigned short* vTbf   = (unsigned short*)take((size_t)64 * 64 * 512 * 2);
  unsigned short* ctxbf  = (unsigned short*)take((size_t)BL * 512 * 2);
  unsigned short* ff1bf  = (unsigned short*)take((size_t)BL * 2048 * 2);
  unsigned short* Wqkvb  = (unsigned short*)take((size_t)4 * 1536 * 512 * 2);
  unsigned short* Wob    = (unsigned short*)take((size_t)4 * 512 * 512 * 2);
  unsigned short* W1b    = (unsigned short*)take((size_t)4 * 2048 * 512 * 2);
  unsigned short* W2b    = (unsigned short*)take((size_t)4 * 512 * 2048 * 2);

  f2b_arr<<<2048, 256, 0, stream>>>(Wqkv, Wqkvb, 4L * 1536 * 512);
  f2b_arr<<<1024, 256, 0, stream>>>(Wo,   Wob,   4L * 512 * 512);
  f2b_arr<<<2048, 256, 0, stream>>>(W1,   W1b,   4L * 2048 * 512);
  f2b_arr<<<2048, 256, 0, stream>>>(W2,   W2b,   4L * 512 * 2048);
  copy_conv<<<2048, 256, 0, stream>>>(src, x, xbf, (long)BL * 512);

  float* out_x    = (float*)d_out;
  float* out_attn = out_x + (size_t)BL * 512;

  for (int i = 0; i < NL_; ++i) {
    // QKV: [4096,1536] = x @ Wqkv^T + bqkv   (bf16 out)
    gemm_bt<128, 128, 4, 4><<<dim3(BL / 128, 1536 / 128, 1), 256, 0, stream>>>(
        xbf, 512, 0, 0, Wqkvb + (size_t)i * 1536 * 512, 512, 0, 0,
        nullptr, qkvbf, 1536, 0, 0, bqkv + (size_t)i * 1536, 512, 1.f, 0, 1);

    pack_vT<<<dim3(64, 128), 256, 0, stream>>>(qkvbf, vTbf);

    // scores: per (b,h) 512x512x64, scale=1/8, fp32 straight into d_out attn slot
    float* attnL = out_attn + (size_t)i * 64 * 512 * 512;
    gemm_bt<128, 128, 4, 4><<<dim3(4, 4, 64), 256, 0, stream>>>(
        qkvbf, 1536, 786432L, 64L,
        qkvbf + 512, 1536, 786432L, 64L,
        attnL, nullptr, 512, 2097152L, 262144L,
        nullptr, 64, 0.125f, 0, 8);

    softmax_rows<<<32768, 256, 0, stream>>>(attnL, attnbf);

    // ctx: per (b,h) [512,64] = attn @ v ; write as [4096,512] bf16
    gemm_bt<128, 64, 4, 2><<<dim3(4, 1, 64), 256, 0, stream>>>(
        attnbf, 512, 2097152L, 262144L,
        vTbf, 512, 262144L, 32768L,
        nullptr, ctxbf, 512, 262144L, 64L,
        nullptr, 512, 1.f, 0, 8);

    // attn_out = ctx @ Wo^T + bo  (fp32)
    gemm_bt<128, 128, 4, 4><<<dim3(32, 4, 1), 256, 0, stream>>>(
        ctxbf, 512, 0, 0, Wob + (size_t)i * 512 * 512, 512, 0, 0,
        attn_out, nullptr, 512, 0, 0, bo + (size_t)i * 512, 512, 1.f, 0, 1);

    // x1 = LN(x + attn_out)
    resid_ln<<<BL, 256, 0, stream>>>(x, attn_out, g1 + (size_t)i * 512, be1 + (size_t)i * 512, x1, xbf);

    // ff1 = relu(x1 @ W1^T + b1)  (bf16)
    gemm_bt<128, 128, 4, 4><<<dim3(32, 16, 1), 256, 0, stream>>>(
        xbf, 512, 0, 0, W1b + (size_t)i * 2048 * 512, 512, 0, 0,
        nullptr, ff1bf, 2048, 0, 0, b1 + (size_t)i * 2048, 512, 1.f, 1, 1);

    // ff2 = ff1 @ W2^T + b2  (fp32)
    gemm_bt<128, 128, 4, 4><<<dim3(32, 4, 1), 256, 0, stream>>>(
        ff1bf, 2048, 0, 0, W2b + (size_t)i * 512 * 2048, 2048, 0, 0,
        ff2, nullptr, 512, 0, 0, b2 + (size_t)i * 512, 2048, 1.f, 0, 1);

    // x = LN(x1 + ff2); final layer writes straight to d_out
    resid_ln<<<BL, 256, 0, stream>>>(x1, ff2, g2 + (size_t)i * 512, be2 + (size_t)i * 512,
                                     (i == 3) ? out_x : x, xbf);
  }
}

// Round 2
// 974.243 us; speedup vs baseline: 1.1322x; 1.1322x over previous
//
// Round 2: global_load_lds (width=16) staging in gemm_bt; fused scores+softmax
// kernel (eliminates 64MB fp32 intermediate write+read per layer); vectorized LN.
#include <hip/hip_runtime.h>
#include <hip/hip_bf16.h>

#define B_ 8
#define L_ 512
#define D_ 512
#define H_ 8
#define F_ 2048
#define NL_ 4
#define BL 4096            // B_*L_
#define EPS_ 1e-5f

typedef __bf16 bf16_t;
typedef bf16_t bf16x8 __attribute__((ext_vector_type(8)));
typedef float f32x4 __attribute__((ext_vector_type(4)));
typedef unsigned short u16x4 __attribute__((ext_vector_type(4)));

__device__ __forceinline__ unsigned short f2b_rn(float f) {
  unsigned u = __builtin_bit_cast(unsigned, f);
  u = (u + 0x7fffu + ((u >> 16) & 1u)) >> 16;
  return (unsigned short)u;
}

// async global->LDS, 16B per lane. LDS dest must be wave-uniform base + lane*16.
__device__ __forceinline__ void gload_lds16(const unsigned short* g, unsigned short* l) {
  __builtin_amdgcn_global_load_lds(
      (const __attribute__((address_space(1))) void*)g,
      (__attribute__((address_space(3))) void*)l, 16, 0, 0);
}

// C[M,N] = relu?(scale * A[M,K] @ B[N,K]^T + bias[N]); optional fp32 and bf16 outputs.
// Batched via blockIdx.z with (z/zi, z%zi) stride decomposition for A/B/C.
template<int BM, int BN, int MT, int NT>
__global__ __launch_bounds__(256)
void gemm_bt(const unsigned short* __restrict__ A, int lda, long sAo, long sAi,
             const unsigned short* __restrict__ Bm, int ldb, long sBo, long sBi,
             float* __restrict__ Cf, unsigned short* __restrict__ Cb, int ldc,
             long sCo, long sCi,
             const float* __restrict__ bias, int K, float scale, int relu, int zi)
{
  static_assert(BM == MT * 32 && BN == NT * 32, "waves are 2x2");
  __shared__ unsigned short As[BM * 32];
  __shared__ unsigned short Bs[BN * 32];
  const int tid  = threadIdx.x;
  const int lane = tid & 63;
  const int wave = tid >> 6;
  const int wm = (wave >> 1) * (MT * 16);
  const int wn = (wave & 1) * (NT * 16);
  const int m0 = blockIdx.x * BM;
  const int n0 = blockIdx.y * BN;
  const int z  = blockIdx.z;
  const long offA = (long)(z / zi) * sAo + (long)(z % zi) * sAi;
  const long offB = (long)(z / zi) * sBo + (long)(z % zi) * sBi;
  const long offC = (long)(z / zi) * sCo + (long)(z % zi) * sCi;

  f32x4 acc[MT][NT] = {};

  for (int k0 = 0; k0 < K; k0 += 32) {
    __syncthreads();
#pragma unroll
    for (int j = 0; j < BM / 64; ++j) {
      int c = tid + j * 256;
      int r = c >> 2, cc = (c & 3) * 8;
      gload_lds16(A + offA + (long)(m0 + r) * lda + (k0 + cc), &As[c * 8]);
    }
#pragma unroll
    for (int j = 0; j < BN / 64; ++j) {
      int c = tid + j * 256;
      int r = c >> 2, cc = (c & 3) * 8;
      gload_lds16(Bm + offB + (long)(n0 + r) * ldb + (k0 + cc), &Bs[c * 8]);
    }
    __syncthreads();
    bf16x8 af[MT], bfr[NT];
#pragma unroll
    for (int mt = 0; mt < MT; ++mt)
      af[mt] = *(const bf16x8*)(&As[(wm + mt * 16 + (lane & 15)) * 32 + (lane >> 4) * 8]);
#pragma unroll
    for (int nt = 0; nt < NT; ++nt)
      bfr[nt] = *(const bf16x8*)(&Bs[(wn + nt * 16 + (lane & 15)) * 32 + (lane >> 4) * 8]);
#pragma unroll
    for (int mt = 0; mt < MT; ++mt)
#pragma unroll
      for (int nt = 0; nt < NT; ++nt)
        acc[mt][nt] = __builtin_amdgcn_mfma_f32_16x16x32_bf16(af[mt], bfr[nt], acc[mt][nt], 0, 0, 0);
  }

  // C/D layout: col=lane&15, row=(lane>>4)*4+r
#pragma unroll
  for (int nt = 0; nt < NT; ++nt) {
    const int col = n0 + wn + nt * 16 + (lane & 15);
    const float bb = bias ? bias[col] : 0.f;
#pragma unroll
    for (int mt = 0; mt < MT; ++mt) {
#pragma unroll
      for (int r = 0; r < 4; ++r) {
        const int row = m0 + wm + mt * 16 + (lane >> 4) * 4 + r;
        float v = acc[mt][nt][r] * scale + bb;
        if (relu) v = fmaxf(v, 0.f);
        const long o = offC + (long)row * ldc + col;
        if (Cf) Cf[o] = v;
        if (Cb) Cb[o] = f2b_rn(v);
      }
    }
  }
}

// Fused scores + softmax: per (row-block of 64, z=(b*8+h)) computes full 512-wide
// softmax(QK^T/8) rows in registers; writes fp32 attn (d_out) + bf16 copy (ws).
__global__ __launch_bounds__(256)
void attn_scores_softmax(const unsigned short* __restrict__ qkv,
                         float* __restrict__ attnf, unsigned short* __restrict__ attnb) {
  __shared__ unsigned short Qs[64 * 64];
  __shared__ unsigned short Ks[512 * 64];
  const int tid = threadIdx.x, lane = tid & 63, wave = tid >> 6;
  const int q0 = blockIdx.x * 64;
  const int z = blockIdx.y, b = z >> 3, h = z & 7;
  const unsigned short* qbase = qkv + (long)b * 512 * 1536 + h * 64;
  const unsigned short* kbase = qbase + 512;
#pragma unroll
  for (int j = 0; j < 2; ++j) {            // Q [64,64]
    int c = tid + j * 256;
    int r = c >> 3, cc = (c & 7) * 8;
    gload_lds16(qbase + (long)(q0 + r) * 1536 + cc, &Qs[c * 8]);
  }
#pragma unroll
  for (int j = 0; j < 16; ++j) {           // K [512,64]
    int c = tid + j * 256;
    int r = c >> 3, cc = (c & 7) * 8;
    gload_lds16(kbase + (long)r * 1536 + cc, &Ks[c * 8]);
  }
  __syncthreads();

  const bf16x8 af0 = *(const bf16x8*)&Qs[(wave * 16 + (lane & 15)) * 64 + (lane >> 4) * 8];
  const bf16x8 af1 = *(const bf16x8*)&Qs[(wave * 16 + (lane & 15)) * 64 + 32 + (lane >> 4) * 8];

  f32x4 acc[32];
#pragma unroll
  for (int st = 0; st < 32; ++st) {
    f32x4 a = {};
    const bf16x8 b0 = *(const bf16x8*)&Ks[(st * 16 + (lane & 15)) * 64 + (lane >> 4) * 8];
    const bf16x8 b1 = *(const bf16x8*)&Ks[(st * 16 + (lane & 15)) * 64 + 32 + (lane >> 4) * 8];
    a = __builtin_amdgcn_mfma_f32_16x16x32_bf16(af0, b0, a, 0, 0, 0);
    a = __builtin_amdgcn_mfma_f32_16x16x32_bf16(af1, b1, a, 0, 0, 0);
    acc[st] = a;
  }
  // scale + row softmax. Row r's 512 values live in 16 lanes (lane&15) x 32 st.
  float mx[4] = {-1e30f, -1e30f, -1e30f, -1e30f};
#pragma unroll
  for (int st = 0; st < 32; ++st)
#pragma unroll
    for (int r = 0; r < 4; ++r) {
      acc[st][r] *= 0.125f;
      mx[r] = fmaxf(mx[r], acc[st][r]);
    }
#pragma unroll
  for (int msk = 1; msk < 16; msk <<= 1)
#pragma unroll
    for (int r = 0; r < 4; ++r) mx[r] = fmaxf(mx[r], __shfl_xor(mx[r], msk));
  float sm[4] = {0.f, 0.f, 0.f, 0.f};
#pragma unroll
  for (int st = 0; st < 32; ++st)
#pragma unroll
    for (int r = 0; r < 4; ++r) {
      const float e = __expf(acc[st][r] - mx[r]);
      acc[st][r] = e;
      sm[r] += e;
    }
#pragma unroll
  for (int msk = 1; msk < 16; msk <<= 1)
#pragma unroll
    for (int r = 0; r < 4; ++r) sm[r] += __shfl_xor(sm[r], msk);
  float inv[4];
#pragma unroll
  for (int r = 0; r < 4; ++r) inv[r] = 1.f / sm[r];

  const long obase = (long)z * 262144 + (long)(q0 + wave * 16 + (lane >> 4) * 4) * 512 + (lane & 15);
#pragma unroll
  for (int st = 0; st < 32; ++st)
#pragma unroll
    for (int r = 0; r < 4; ++r) {
      const float v = acc[st][r] * inv[r];
      const long o = obase + (long)r * 512 + st * 16;
      attnf[o] = v;
      attnb[o] = f2b_rn(v);
    }
}

// out = LayerNorm(a + b) * g + be ; fp32 + bf16, float4-vectorized, 128 threads.
__global__ __launch_bounds__(128)
void resid_ln(const float* __restrict__ a, const float* __restrict__ b,
              const float* __restrict__ g, const float* __restrict__ be,
              float* __restrict__ outf, unsigned short* __restrict__ outb) {
  const long row = blockIdx.x;
  const int t = threadIdx.x;
  const int wave = t >> 6, lane = t & 63;
  const f32x4 va = *(const f32x4*)&a[row * 512 + t * 4];
  const f32x4 vb = *(const f32x4*)&b[row * 512 + t * 4];
  f32x4 v;
  float s = 0.f, s2 = 0.f;
#pragma unroll
  for (int i = 0; i < 4; ++i) { v[i] = va[i] + vb[i]; s += v[i]; s2 += v[i] * v[i]; }
  for (int o = 32; o > 0; o >>= 1) { s += __shfl_down(s, o); s2 += __shfl_down(s2, o); }
  __shared__ float red[4];
  if (lane == 0) { red[wave] = s; red[2 + wave] = s2; }
  __syncthreads();
  s = red[0] + red[1];
  s2 = red[2] + red[3];
  const float mu  = s * (1.f / 512.f);
  const float var = s2 * (1.f / 512.f) - mu * mu;
  const float ri = rsqrtf(var + EPS_);
  const f32x4 vg = *(const f32x4*)&g[t * 4];
  const f32x4 ve = *(const f32x4*)&be[t * 4];
  f32x4 y;
  u16x4 yb;
#pragma unroll
  for (int i = 0; i < 4; ++i) { y[i] = (v[i] - mu) * ri * vg[i] + ve[i]; yb[i] = f2b_rn(y[i]); }
  *(f32x4*)&outf[row * 512 + t * 4] = y;
  *(u16x4*)&outb[row * 512 + t * 4] = yb;
}

// vT[z][d][s] = qkv[(b*512+s)*1536 + 1024 + h*64 + d]
__global__ __launch_bounds__(256)
void pack_vT(const unsigned short* __restrict__ qkv, unsigned short* __restrict__ vT) {
  const int z = blockIdx.x;
  const int bb = z >> 3, h = z & 7;
  const int idx = blockIdx.y * 256 + threadIdx.x;
  const int d = idx >> 9, s = idx & 511;
  vT[(long)z * 32768 + idx] = qkv[((long)(bb * 512 + s)) * 1536 + 1024 + h * 64 + d];
}

__global__ void f2b_arr(const float* __restrict__ in, unsigned short* __restrict__ out, long n4) {
  long i = (long)blockIdx.x * 256 + threadIdx.x;
  const long stride = (long)gridDim.x * 256;
  for (; i < n4; i += stride) {
    const f32x4 v = *(const f32x4*)&in[i * 4];
    u16x4 o;
#pragma unroll
    for (int k = 0; k < 4; ++k) o[k] = f2b_rn(v[k]);
    *(u16x4*)&out[i * 4] = o;
  }
}

__global__ void copy_conv(const float* __restrict__ in, float* __restrict__ outf,
                          unsigned short* __restrict__ outb, long n4) {
  long i = (long)blockIdx.x * 256 + threadIdx.x;
  const long stride = (long)gridDim.x * 256;
  for (; i < n4; i += stride) {
    const f32x4 v = *(const f32x4*)&in[i * 4];
    u16x4 o;
#pragma unroll
    for (int k = 0; k < 4; ++k) o[k] = f2b_rn(v[k]);
    *(f32x4*)&outf[i * 4] = v;
    *(u16x4*)&outb[i * 4] = o;
  }
}

extern "C" void kernel_launch(void* const* d_in, const int* in_sizes, int n_in,
                              void* d_out, int out_size, void* d_ws, size_t ws_size,
                              hipStream_t stream) {
  const float* src  = (const float*)d_in[0];
  const float* Wqkv = (const float*)d_in[1];
  const float* bqkv = (const float*)d_in[2];
  const float* Wo   = (const float*)d_in[3];
  const float* bo   = (const float*)d_in[4];
  const float* W1   = (const float*)d_in[5];
  const float* b1   = (const float*)d_in[6];
  const float* W2   = (const float*)d_in[7];
  const float* b2   = (const float*)d_in[8];
  const float* g1   = (const float*)d_in[9];
  const float* be1  = (const float*)d_in[10];
  const float* g2   = (const float*)d_in[11];
  const float* be2  = (const float*)d_in[12];

  char* p = (char*)d_ws;
  auto take = [&](size_t bytes) { void* r = (void*)p; p += (bytes + 255) & ~(size_t)255; return r; };
  float* x        = (float*)take((size_t)BL * 512 * 4);
  float* x1       = (float*)take((size_t)BL * 512 * 4);
  float* attn_out = (float*)take((size_t)BL * 512 * 4);
  float* ff2      = (float*)take((size_t)BL * 512 * 4);
  unsigned short* xbf    = (unsigned short*)take((size_t)BL * 512 * 2);
  unsigned short* qkvbf  = (unsigned short*)take((size_t)BL * 1536 * 2);
  unsigned short* attnbf = (unsigned short*)take((size_t)64 * 512 * 512 * 2);
  unsigned short* vTbf   = (unsigned short*)take((size_t)64 * 64 * 512 * 2);
  unsigned short* ctxbf  = (unsigned short*)take((size_t)BL * 512 * 2);
  unsigned short* ff1bf  = (unsigned short*)take((size_t)BL * 2048 * 2);
  unsigned short* Wqkvb  = (unsigned short*)take((size_t)4 * 1536 * 512 * 2);
  unsigned short* Wob    = (unsigned short*)take((size_t)4 * 512 * 512 * 2);
  unsigned short* W1b    = (unsigned short*)take((size_t)4 * 2048 * 512 * 2);
  unsigned short* W2b    = (unsigned short*)take((size_t)4 * 512 * 2048 * 2);

  f2b_arr<<<1024, 256, 0, stream>>>(Wqkv, Wqkvb, 4L * 1536 * 512 / 4);
  f2b_arr<<<512,  256, 0, stream>>>(Wo,   Wob,   4L * 512 * 512 / 4);
  f2b_arr<<<1024, 256, 0, stream>>>(W1,   W1b,   4L * 2048 * 512 / 4);
  f2b_arr<<<1024, 256, 0, stream>>>(W2,   W2b,   4L * 512 * 2048 / 4);
  copy_conv<<<1024, 256, 0, stream>>>(src, x, xbf, (long)BL * 512 / 4);

  float* out_x    = (float*)d_out;
  float* out_attn = out_x + (size_t)BL * 512;

  for (int i = 0; i < NL_; ++i) {
    // QKV: [4096,1536] = x @ Wqkv^T + bqkv   (bf16 out)
    gemm_bt<128, 128, 4, 4><<<dim3(BL / 128, 1536 / 128, 1), 256, 0, stream>>>(
        xbf, 512, 0, 0, Wqkvb + (size_t)i * 1536 * 512, 512, 0, 0,
        nullptr, qkvbf, 1536, 0, 0, bqkv + (size_t)i * 1536, 512, 1.f, 0, 1);

    pack_vT<<<dim3(64, 128), 256, 0, stream>>>(qkvbf, vTbf);

    // fused scores + softmax -> d_out attn slot (fp32) + attnbf (bf16)
    float* attnL = out_attn + (size_t)i * 64 * 512 * 512;
    attn_scores_softmax<<<dim3(8, 64), 256, 0, stream>>>(qkvbf, attnL, attnbf);

    // ctx: per (b,h) [512,64] = attn @ v ; write as [4096,512] bf16
    gemm_bt<128, 64, 4, 2><<<dim3(4, 1, 64), 256, 0, stream>>>(
        attnbf, 512, 2097152L, 262144L,
        vTbf, 512, 262144L, 32768L,
        nullptr, ctxbf, 512, 262144L, 64L,
        nullptr, 512, 1.f, 0, 8);

    // attn_out = ctx @ Wo^T + bo  (fp32)  [128x64 tile -> 256 blocks]
    gemm_bt<128, 64, 4, 2><<<dim3(32, 8, 1), 256, 0, stream>>>(
        ctxbf, 512, 0, 0, Wob + (size_t)i * 512 * 512, 512, 0, 0,
        attn_out, nullptr, 512, 0, 0, bo + (size_t)i * 512, 512, 1.f, 0, 1);

    // x1 = LN(x + attn_out)
    resid_ln<<<BL, 128, 0, stream>>>(x, attn_out, g1 + (size_t)i * 512, be1 + (size_t)i * 512, x1, xbf);

    // ff1 = relu(x1 @ W1^T + b1)  (bf16)
    gemm_bt<128, 128, 4, 4><<<dim3(32, 16, 1), 256, 0, stream>>>(
        xbf, 512, 0, 0, W1b + (size_t)i * 2048 * 512, 512, 0, 0,
        nullptr, ff1bf, 2048, 0, 0, b1 + (size_t)i * 2048, 512, 1.f, 1, 1);

    // ff2 = ff1 @ W2^T + b2  (fp32)  [128x64 tile -> 256 blocks]
    gemm_bt<128, 64, 4, 2><<<dim3(32, 8, 1), 256, 0, stream>>>(
        ff1bf, 2048, 0, 0, W2b + (size_t)i * 512 * 2048, 2048, 0, 0,
        ff2, nullptr, 512, 0, 0, b2 + (size_t)i * 512, 2048, 1.f, 0, 1);

    // x = LN(x1 + ff2); final layer writes straight to d_out
    resid_ln<<<BL, 128, 0, stream>>>(x1, ff2, g2 + (size_t)i * 512, be2 + (size_t)i * 512,
                                     (i == 3) ? out_x : x, xbf);
  }
}